// Round 3
// baseline (1301.482 us; speedup 1.0000x reference)
//
#include <hip/hip_runtime.h>

#define NF   128
#define C1   16
#define C2   32
#define NCLS 10
#define MAXBUCK 512     // buckets of 256 nodes; N=100000 -> 391
#define TILE 4096

// ============ degree ============

__global__ void k_hist(const int* __restrict__ ei, int* __restrict__ cnt, int E) {
    int e = blockIdx.x * blockDim.x + threadIdx.x;
    if (e < E) atomicAdd(&cnt[ei[E + e]], 1);   // in-degree by dst
}

__global__ void k_dinv(const int* __restrict__ cnt, float* __restrict__ dinv, int N) {
    int i = blockIdx.x * blockDim.x + threadIdx.x;
    if (i < N) dinv[i] = rsqrtf((float)cnt[i] + 1.0f);  // +1 self-loop
}

// bucket counts = reduce of per-node counts over each 256-node range
__global__ __launch_bounds__(256) void k_bucket_cnt(const int* __restrict__ cnt,
                                                    int* __restrict__ bcount, int N) {
    __shared__ int sh[4];
    int b = blockIdx.x;
    int n = b * 256 + threadIdx.x;
    int v = (n < N) ? cnt[n] : 0;
    for (int off = 32; off >= 1; off >>= 1) v += __shfl_down(v, off);
    if ((threadIdx.x & 63) == 0) sh[threadIdx.x >> 6] = v;
    __syncthreads();
    if (threadIdx.x == 0) bcount[b] = sh[0] + sh[1] + sh[2] + sh[3];
}

// exclusive scan of bucket counts -> bbase[0..nbuck]; also init fill = bbase
__global__ __launch_bounds__(512) void k_bucket_scan(const int* __restrict__ bcount,
                                                     int* __restrict__ bbase,
                                                     int* __restrict__ fill,
                                                     int nbuck, int E) {
    __shared__ int sh[512];
    int tid = threadIdx.x;
    int v = (tid < nbuck) ? bcount[tid] : 0;
    sh[tid] = v;
    __syncthreads();
    for (int off = 1; off < 512; off <<= 1) {
        int t = (tid >= off) ? sh[tid - off] : 0;
        __syncthreads();
        sh[tid] += t;
        __syncthreads();
    }
    if (tid < nbuck) {
        int ex = sh[tid] - v;
        bbase[tid] = ex;
        fill[tid] = ex;
    }
    if (tid == 0) bbase[nbuck] = E;
}

// ============ bucketed edge binning (two-level counting sort, coarse pass) ============
// packs edge as src | (dst&255)<<17 into bucket-ordered array

__global__ __launch_bounds__(256) void k_bscatter(const int* __restrict__ ei,
                                                  int* __restrict__ fill,
                                                  int* __restrict__ packed_out,
                                                  int E, int nbuck) {
    __shared__ int hist[MAXBUCK];
    __shared__ int off0[MAXBUCK];
    __shared__ int cur[MAXBUCK];
    __shared__ int basev[MAXBUCK];
    __shared__ int stage[TILE];            // 16 KB
    __shared__ unsigned short bkt[TILE];   // 8 KB
    int tid = threadIdx.x;
    long long t0 = (long long)blockIdx.x * TILE;

    for (int i = tid; i < MAXBUCK; i += 256) hist[i] = 0;
    __syncthreads();
    for (int i = tid; i < TILE; i += 256) {
        long long e = t0 + i;
        if (e < E) atomicAdd(&hist[ei[E + e] >> 8], 1);
    }
    __syncthreads();
    // exclusive scan of hist[0..MAXBUCK) by wave 0 (8 chunks of 64)
    if (tid < 64) {
        int carry = 0;
        for (int c = 0; c < MAXBUCK / 64; ++c) {
            int idx = c * 64 + tid;
            int v = hist[idx];
            int orig = v;
            for (int off = 1; off < 64; off <<= 1) {
                int t = __shfl_up(v, off);
                if (tid >= off) v += t;
            }
            off0[idx] = v - orig + carry;
            carry += __shfl(v, 63);
        }
    }
    __syncthreads();
    // reserve global space per bucket; init local cursors
    for (int i = tid; i < nbuck; i += 256) {
        int h = hist[i];
        basev[i] = h ? atomicAdd(&fill[i], h) : 0;
        cur[i] = off0[i];
    }
    __syncthreads();
    // place into stage, bucket-ordered
    for (int i = tid; i < TILE; i += 256) {
        long long e = t0 + i;
        if (e < E) {
            int d = ei[E + e];
            int s = ei[e];
            int b = d >> 8;
            int slot = atomicAdd(&cur[b], 1);
            stage[slot] = s | ((d & 255) << 17);
            bkt[slot] = (unsigned short)b;
        }
    }
    __syncthreads();
    // coalesced-run copy out
    int m = (int)min((long long)TILE, (long long)E - t0);
    for (int i = tid; i < m; i += 256) {
        int b = bkt[i];
        packed_out[basev[b] + (i - off0[b])] = stage[i];
    }
}

// ============ linear layers (write y = h * dinv) ============

__global__ __launch_bounds__(256) void k_lin1(const float* __restrict__ x,
                                              const float* __restrict__ W1,
                                              const float* __restrict__ dinv,
                                              float* __restrict__ y1, int N) {
    __shared__ float ws[NF * C1];
    __shared__ float xs[16 * 132];
    int tid = threadIdx.x;
    for (int t = tid; t < NF * C1; t += 256) ws[t] = W1[t];
    int n0 = blockIdx.x * 16;
    for (int t = tid; t < 16 * NF; t += 256) {
        int r = t >> 7, c = t & 127;
        int n = n0 + r;
        xs[r * 132 + c] = (n < N) ? x[(size_t)n * NF + c] : 0.0f;
    }
    __syncthreads();
    int r = tid >> 4, j = tid & 15;
    float acc = 0.0f;
#pragma unroll 4
    for (int k = 0; k < NF; ++k) acc += xs[r * 132 + k] * ws[k * C1 + j];
    int n = n0 + r;
    if (n < N) y1[(size_t)n * C1 + j] = acc * dinv[n];
}

__global__ __launch_bounds__(256) void k_lin2(const float* __restrict__ agg1,
                                              const float* __restrict__ b1,
                                              const float* __restrict__ W2,
                                              const float* __restrict__ dinv,
                                              float* __restrict__ y2, int N) {
    __shared__ float ws[C1 * C2];
    __shared__ float hs[8 * C1];
    int tid = threadIdx.x;
    for (int t = tid; t < C1 * C2; t += 256) ws[t] = W2[t];
    int n0 = blockIdx.x * 8;
    if (tid < 8 * C1) {
        int r = tid >> 4, j = tid & 15;
        int n = n0 + r;
        hs[tid] = (n < N) ? fmaxf(agg1[(size_t)n * C1 + j] + b1[j], 0.0f) : 0.0f;
    }
    __syncthreads();
    int r = tid >> 5, i = tid & 31;
    float acc = 0.0f;
#pragma unroll
    for (int j = 0; j < C1; ++j) acc += hs[r * C1 + j] * ws[j * C2 + i];
    int n = n0 + r;
    if (n < N) y2[(size_t)n * C2 + i] = acc * dinv[n];
}

// ============ bucketed aggregation: one block per 256-node bucket ============
// agg[n] = dinv[n] * (y[n] + sum_{edges with dst=n} y[src])

template <int LOGC>
__global__ __launch_bounds__(256) void k_bagg(const int* __restrict__ packed,
                                              const int* __restrict__ bbase,
                                              const float* __restrict__ dinv,
                                              const float* __restrict__ y,
                                              float* __restrict__ agg, int N) {
    const int C = 1 << LOGC;
    const int NG = 256 >> LOGC;          // edge groups per block
    __shared__ float accum[256 * ((1 << LOGC) + 1)];  // padded stride C+1
    __shared__ int pe[256];
    int tid = threadIdx.x;
    int b = blockIdx.x;
    int n0 = b * 256;
    int nn = min(256, N - n0);

    for (int i = tid; i < 256 * (C + 1); i += 256) accum[i] = 0.0f;

    int e0 = bbase[b], e1 = bbase[b + 1];
    int lane_j = tid & (C - 1);
    int grp = tid >> LOGC;

    for (int be = e0; be < e1; be += 256) {
        int m = min(256, e1 - be);
        __syncthreads();
        if (tid < m) pe[tid] = packed[be + tid];
        __syncthreads();
        for (int k = grp; k < m; k += NG) {
            int p = pe[k];
            int src = p & 0x1FFFF;
            int ld = p >> 17;
            atomicAdd(&accum[ld * (C + 1) + lane_j], y[(size_t)src * C + lane_j]);
        }
    }
    __syncthreads();
    for (int i = tid; i < nn * C; i += 256) {
        int ln = i >> LOGC, j = i & (C - 1);
        int n = n0 + ln;
        agg[(size_t)n * C + j] = dinv[n] * (accum[ln * (C + 1) + j] + y[(size_t)n * C + j]);
    }
}

// ============ per-graph mean pool (sorted batch) + fused FC ============

__global__ __launch_bounds__(256) void k_pool_fc(const float* __restrict__ agg2,
                                                 const float* __restrict__ b2,
                                                 const int* __restrict__ batch,
                                                 const float* __restrict__ Wfc,
                                                 const float* __restrict__ bfc,
                                                 float* __restrict__ out, int N, int G) {
    int g = blockIdx.x;
    int lo = 0, hi = N;
    while (lo < hi) { int m = (lo + hi) >> 1; if (batch[m] < g) lo = m + 1; else hi = m; }
    int start = lo;
    lo = start; hi = N;
    while (lo < hi) { int m = (lo + hi) >> 1; if (batch[m] < g + 1) lo = m + 1; else hi = m; }
    int end = lo;

    int tid = threadIdx.x;
    int i = tid & 31, r = tid >> 5;
    float bi = b2[i];
    float acc = 0.0f;
    for (int n = start + r; n < end; n += 8)
        acc += fmaxf(agg2[(size_t)n * C2 + i] + bi, 0.0f);

    __shared__ float red[256];
    red[tid] = acc;
    __syncthreads();
    for (int s = 4; s >= 1; s >>= 1) {
        if (r < s) red[tid] += red[tid + s * 32];
        __syncthreads();
    }
    __shared__ float pooled[C2];
    if (tid < C2) {
        float cnt = (float)(end - start);
        pooled[tid] = red[tid] / fmaxf(cnt, 1.0f);
    }
    __syncthreads();
    if (tid < NCLS) {
        float a = bfc[tid];
#pragma unroll
        for (int j = 0; j < C2; ++j) a += pooled[j] * Wfc[j * NCLS + tid];
        out[g * NCLS + tid] = a;
    }
}

extern "C" void kernel_launch(void* const* d_in, const int* in_sizes, int n_in,
                              void* d_out, int out_size, void* d_ws, size_t ws_size,
                              hipStream_t stream) {
    const float* x    = (const float*)d_in[0];
    const int*   ei   = (const int*)d_in[1];
    const int*   batch= (const int*)d_in[2];
    const float* W1   = (const float*)d_in[3];
    const float* b1   = (const float*)d_in[4];
    const float* W2   = (const float*)d_in[5];
    const float* b2   = (const float*)d_in[6];
    const float* Wfc  = (const float*)d_in[7];
    const float* bfc  = (const float*)d_in[8];
    float* out = (float*)d_out;

    const int N = in_sizes[0] / NF;        // 100000
    const int E = in_sizes[1] / 2;         // 3200000
    const int G = out_size / NCLS;         // 256
    const int nbuck = (N + 255) >> 8;      // 391

    char* p = (char*)d_ws;
    auto alloc = [&](size_t bytes) { char* q = p; p += (bytes + 15) & ~(size_t)15; return q; };
    int*   cnt    = (int*)  alloc((size_t)N * 4);
    float* dinv   = (float*)alloc((size_t)N * 4);
    int*   bcount = (int*)  alloc(MAXBUCK * 4);
    int*   bbase  = (int*)  alloc((MAXBUCK + 1) * 4);
    int*   fill   = (int*)  alloc(MAXBUCK * 4);
    int*   packed = (int*)  alloc((size_t)E * 4);
    float* y1     = (float*)alloc((size_t)N * C1 * 4);
    float* agg1   = (float*)alloc((size_t)N * C1 * 4);
    float* y2     = (float*)alloc((size_t)N * C2 * 4);
    float* agg2   = (float*)alloc((size_t)N * C2 * 4);

    const int B = 256;

    hipMemsetAsync(cnt, 0, (size_t)N * 4, stream);
    k_hist<<<(E + B - 1) / B, B, 0, stream>>>(ei, cnt, E);
    k_dinv<<<(N + B - 1) / B, B, 0, stream>>>(cnt, dinv, N);
    k_bucket_cnt<<<nbuck, B, 0, stream>>>(cnt, bcount, N);
    k_bucket_scan<<<1, 512, 0, stream>>>(bcount, bbase, fill, nbuck, E);
    k_bscatter<<<(E + TILE - 1) / TILE, B, 0, stream>>>(ei, fill, packed, E, nbuck);

    k_lin1<<<(N + 15) / 16, B, 0, stream>>>(x, W1, dinv, y1, N);
    k_bagg<4><<<nbuck, B, 0, stream>>>(packed, bbase, dinv, y1, agg1, N);

    k_lin2<<<(N + 7) / 8, B, 0, stream>>>(agg1, b1, W2, dinv, y2, N);
    k_bagg<5><<<nbuck, B, 0, stream>>>(packed, bbase, dinv, y2, agg2, N);

    k_pool_fc<<<G, B, 0, stream>>>(agg2, b2, batch, Wfc, bfc, out, N, G);
}

// Round 4
// 324.034 us; speedup vs baseline: 4.0165x; 4.0165x over previous
//
#include <hip/hip_runtime.h>

#define NF   128
#define C1   16
#define C2   32
#define NCLS 10
#define MAXBUCK 512     // buckets of 256 nodes; N=100000 -> 391
#define TILE 4096       // edges per k_bscatter block
#define HTILE 8192      // edges per k_bhist block
#define CAP 12288       // LDS stage capacity in k_bsort (mean bucket ~8200)

// ============ bucket histogram (LDS-staged) ============

__global__ __launch_bounds__(256) void k_bhist(const int* __restrict__ ei,
                                               int* __restrict__ bcount, int E, int nbuck) {
    __shared__ int h[MAXBUCK];
    int tid = threadIdx.x;
    for (int i = tid; i < MAXBUCK; i += 256) h[i] = 0;
    __syncthreads();
    long long t0 = (long long)blockIdx.x * HTILE;
    for (int i = tid; i < HTILE; i += 256) {
        long long e = t0 + i;
        if (e < E) atomicAdd(&h[ei[E + e] >> 8], 1);
    }
    __syncthreads();
    for (int i = tid; i < nbuck; i += 256)
        if (h[i]) atomicAdd(&bcount[i], h[i]);
}

// exclusive scan of bucket counts -> bbase[0..nbuck]; init fill = bbase; rowptr[N]=E
__global__ __launch_bounds__(512) void k_bucket_scan(const int* __restrict__ bcount,
                                                     int* __restrict__ bbase,
                                                     int* __restrict__ fill,
                                                     int* __restrict__ rowptr,
                                                     int nbuck, int N, int E) {
    __shared__ int sh[512];
    int tid = threadIdx.x;
    int v = (tid < nbuck) ? bcount[tid] : 0;
    sh[tid] = v;
    __syncthreads();
    for (int off = 1; off < 512; off <<= 1) {
        int t = (tid >= off) ? sh[tid - off] : 0;
        __syncthreads();
        sh[tid] += t;
        __syncthreads();
    }
    if (tid < nbuck) {
        int ex = sh[tid] - v;
        bbase[tid] = ex;
        fill[tid] = ex;
    }
    if (tid == 0) { bbase[nbuck] = E; rowptr[N] = E; }
}

// ============ bucketed edge binning: packed = src | (dst&255)<<17, bucket-contiguous ============

__global__ __launch_bounds__(256) void k_bscatter(const int* __restrict__ ei,
                                                  int* __restrict__ fill,
                                                  int* __restrict__ packed_out,
                                                  int E, int nbuck) {
    __shared__ int hist[MAXBUCK];
    __shared__ int off0[MAXBUCK];
    __shared__ int cur[MAXBUCK];
    __shared__ int basev[MAXBUCK];
    __shared__ int stage[TILE];            // 16 KB
    __shared__ unsigned short bkt[TILE];   // 8 KB
    int tid = threadIdx.x;
    long long t0 = (long long)blockIdx.x * TILE;

    for (int i = tid; i < MAXBUCK; i += 256) hist[i] = 0;
    __syncthreads();
    for (int i = tid; i < TILE; i += 256) {
        long long e = t0 + i;
        if (e < E) atomicAdd(&hist[ei[E + e] >> 8], 1);
    }
    __syncthreads();
    // exclusive scan of hist[0..MAXBUCK) by wave 0 (8 chunks of 64)
    if (tid < 64) {
        int carry = 0;
        for (int c = 0; c < MAXBUCK / 64; ++c) {
            int idx = c * 64 + tid;
            int v = hist[idx];
            int orig = v;
            for (int off = 1; off < 64; off <<= 1) {
                int t = __shfl_up(v, off);
                if (tid >= off) v += t;
            }
            off0[idx] = v - orig + carry;
            carry += __shfl(v, 63);
        }
    }
    __syncthreads();
    for (int i = tid; i < nbuck; i += 256) {
        int h = hist[i];
        basev[i] = h ? atomicAdd(&fill[i], h) : 0;
        cur[i] = off0[i];
    }
    __syncthreads();
    for (int i = tid; i < TILE; i += 256) {
        long long e = t0 + i;
        if (e < E) {
            int d = ei[E + e];
            int s = ei[e];
            int b = d >> 8;
            int slot = atomicAdd(&cur[b], 1);
            stage[slot] = s | ((d & 255) << 17);
            bkt[slot] = (unsigned short)b;
        }
    }
    __syncthreads();
    int m = (int)min((long long)TILE, (long long)E - t0);
    for (int i = tid; i < m; i += 256) {
        int b = bkt[i];
        packed_out[basev[b] + (i - off0[b])] = stage[i];
    }
}

// ============ within-bucket counting sort -> csr_src, rowptr, dinv ============

__global__ __launch_bounds__(256) void k_bsort(const int* __restrict__ packed,
                                               const int* __restrict__ bbase,
                                               int* __restrict__ csr_src,
                                               int* __restrict__ rowptr,
                                               float* __restrict__ dinv, int N) {
    __shared__ int stage[CAP];   // 48 KB
    __shared__ int hcnt[256];
    __shared__ int sh[256];
    __shared__ int cur[256];
    int tid = threadIdx.x, b = blockIdx.x;
    int e0 = bbase[b], e1 = bbase[b + 1], m = e1 - e0;
    int n0 = b << 8;
    hcnt[tid] = 0;
    __syncthreads();
    bool staged = (m <= CAP);
    if (staged) {
        for (int i = tid; i < m; i += 256) {
            int p = packed[e0 + i];
            stage[i] = p;
            atomicAdd(&hcnt[p >> 17], 1);
        }
    } else {
        for (int i = tid; i < m; i += 256)
            atomicAdd(&hcnt[packed[e0 + i] >> 17], 1);
    }
    __syncthreads();
    int v = hcnt[tid];
    sh[tid] = v;
    __syncthreads();
    for (int off = 1; off < 256; off <<= 1) {
        int t = (tid >= off) ? sh[tid - off] : 0;
        __syncthreads();
        sh[tid] += t;
        __syncthreads();
    }
    int ex = sh[tid] - v;     // exclusive within-bucket offset
    cur[tid] = ex;
    int n = n0 + tid;
    if (n < N) {
        rowptr[n] = e0 + ex;
        dinv[n] = rsqrtf((float)v + 1.0f);   // +1 self-loop
    }
    __syncthreads();
    if (staged) {
        for (int i = tid; i < m; i += 256) {
            int p = stage[i];
            int slot = atomicAdd(&cur[p >> 17], 1);
            csr_src[e0 + slot] = p & 0x1FFFF;
        }
    } else {
        for (int i = tid; i < m; i += 256) {
            int p = packed[e0 + i];
            int slot = atomicAdd(&cur[p >> 17], 1);
            csr_src[e0 + slot] = p & 0x1FFFF;
        }
    }
}

// ============ linear layers (write y = h * dinv) ============

__global__ __launch_bounds__(256) void k_lin1(const float* __restrict__ x,
                                              const float* __restrict__ W1,
                                              const float* __restrict__ dinv,
                                              float* __restrict__ y1, int N) {
    __shared__ float ws[NF * C1];
    __shared__ float xs[16 * 132];
    int tid = threadIdx.x;
    for (int t = tid; t < NF * C1; t += 256) ws[t] = W1[t];
    int n0 = blockIdx.x * 16;
    for (int t = tid; t < 16 * NF; t += 256) {
        int r = t >> 7, c = t & 127;
        int n = n0 + r;
        xs[r * 132 + c] = (n < N) ? x[(size_t)n * NF + c] : 0.0f;
    }
    __syncthreads();
    int r = tid >> 4, j = tid & 15;
    float acc = 0.0f;
#pragma unroll 4
    for (int k = 0; k < NF; ++k) acc += xs[r * 132 + k] * ws[k * C1 + j];
    int n = n0 + r;
    if (n < N) y1[(size_t)n * C1 + j] = acc * dinv[n];
}

__global__ __launch_bounds__(256) void k_lin2(const float* __restrict__ agg1,
                                              const float* __restrict__ b1,
                                              const float* __restrict__ W2,
                                              const float* __restrict__ dinv,
                                              float* __restrict__ y2, int N) {
    __shared__ float ws[C1 * C2];
    __shared__ float hs[8 * C1];
    int tid = threadIdx.x;
    for (int t = tid; t < C1 * C2; t += 256) ws[t] = W2[t];
    int n0 = blockIdx.x * 8;
    if (tid < 8 * C1) {
        int r = tid >> 4, j = tid & 15;
        int n = n0 + r;
        hs[tid] = (n < N) ? fmaxf(agg1[(size_t)n * C1 + j] + b1[j], 0.0f) : 0.0f;
    }
    __syncthreads();
    int r = tid >> 5, i = tid & 31;
    float acc = 0.0f;
#pragma unroll
    for (int j = 0; j < C1; ++j) acc += hs[r * C1 + j] * ws[j * C2 + i];
    int n = n0 + r;
    if (n < N) y2[(size_t)n * C2 + i] = acc * dinv[n];
}

// ============ gather aggregation: agg[n] = dinv[n]*(y[n] + sum_{e in row n} y[src]) ============

template <int LOG2C>
__global__ __launch_bounds__(256) void k_gather(const int* __restrict__ rowptr,
                                                const int* __restrict__ csr_src,
                                                const float* __restrict__ dinv,
                                                const float* __restrict__ y,
                                                float* __restrict__ agg, int N) {
    const int C = 1 << LOG2C;
    int tid = threadIdx.x;
    int j = tid & (C - 1);
    int n = blockIdx.x * (256 >> LOG2C) + (tid >> LOG2C);
    if (n >= N) return;
    int k0 = rowptr[n], k1 = rowptr[n + 1];
    float acc0 = y[(size_t)n * C + j];   // self-loop term (already *dinv[n])
    float acc1 = 0.0f;
    int k = k0;
    for (; k + 1 < k1; k += 2) {
        int s0 = csr_src[k], s1 = csr_src[k + 1];
        acc0 += y[(size_t)s0 * C + j];
        acc1 += y[(size_t)s1 * C + j];
    }
    if (k < k1) acc0 += y[(size_t)csr_src[k] * C + j];
    agg[(size_t)n * C + j] = dinv[n] * (acc0 + acc1);
}

// ============ per-graph mean pool (sorted batch) + fused FC ============

__global__ __launch_bounds__(256) void k_pool_fc(const float* __restrict__ agg2,
                                                 const float* __restrict__ b2,
                                                 const int* __restrict__ batch,
                                                 const float* __restrict__ Wfc,
                                                 const float* __restrict__ bfc,
                                                 float* __restrict__ out, int N, int G) {
    int g = blockIdx.x;
    int lo = 0, hi = N;
    while (lo < hi) { int m = (lo + hi) >> 1; if (batch[m] < g) lo = m + 1; else hi = m; }
    int start = lo;
    lo = start; hi = N;
    while (lo < hi) { int m = (lo + hi) >> 1; if (batch[m] < g + 1) lo = m + 1; else hi = m; }
    int end = lo;

    int tid = threadIdx.x;
    int i = tid & 31, r = tid >> 5;
    float bi = b2[i];
    float acc = 0.0f;
    for (int n = start + r; n < end; n += 8)
        acc += fmaxf(agg2[(size_t)n * C2 + i] + bi, 0.0f);

    __shared__ float red[256];
    red[tid] = acc;
    __syncthreads();
    for (int s = 4; s >= 1; s >>= 1) {
        if (r < s) red[tid] += red[tid + s * 32];
        __syncthreads();
    }
    __shared__ float pooled[C2];
    if (tid < C2) {
        float cnt = (float)(end - start);
        pooled[tid] = red[tid] / fmaxf(cnt, 1.0f);
    }
    __syncthreads();
    if (tid < NCLS) {
        float a = bfc[tid];
#pragma unroll
        for (int j = 0; j < C2; ++j) a += pooled[j] * Wfc[j * NCLS + tid];
        out[g * NCLS + tid] = a;
    }
}

extern "C" void kernel_launch(void* const* d_in, const int* in_sizes, int n_in,
                              void* d_out, int out_size, void* d_ws, size_t ws_size,
                              hipStream_t stream) {
    const float* x    = (const float*)d_in[0];
    const int*   ei   = (const int*)d_in[1];
    const int*   batch= (const int*)d_in[2];
    const float* W1   = (const float*)d_in[3];
    const float* b1   = (const float*)d_in[4];
    const float* W2   = (const float*)d_in[5];
    const float* b2   = (const float*)d_in[6];
    const float* Wfc  = (const float*)d_in[7];
    const float* bfc  = (const float*)d_in[8];
    float* out = (float*)d_out;

    const int N = in_sizes[0] / NF;        // 100000
    const int E = in_sizes[1] / 2;         // 3200000
    const int G = out_size / NCLS;         // 256
    const int nbuck = (N + 255) >> 8;      // 391

    char* p = (char*)d_ws;
    auto alloc = [&](size_t bytes) { char* q = p; p += (bytes + 15) & ~(size_t)15; return q; };
    int*   bcount  = (int*)  alloc(MAXBUCK * 4);
    int*   bbase   = (int*)  alloc((MAXBUCK + 1) * 4);
    int*   fill    = (int*)  alloc(MAXBUCK * 4);
    int*   rowptr  = (int*)  alloc((size_t)(N + 1) * 4);
    float* dinv    = (float*)alloc((size_t)N * 4);
    int*   packed  = (int*)  alloc((size_t)E * 4);
    int*   csr_src = (int*)  alloc((size_t)E * 4);
    float* y1      = (float*)alloc((size_t)N * C1 * 4);
    float* agg1    = (float*)alloc((size_t)N * C1 * 4);
    float* y2      = (float*)alloc((size_t)N * C2 * 4);
    float* agg2    = (float*)alloc((size_t)N * C2 * 4);

    const int B = 256;

    // --- CSR build (bucket-staged, no global float atomics, no random 4B scatter) ---
    hipMemsetAsync(bcount, 0, MAXBUCK * 4, stream);
    k_bhist<<<(E + HTILE - 1) / HTILE, B, 0, stream>>>(ei, bcount, E, nbuck);
    k_bucket_scan<<<1, 512, 0, stream>>>(bcount, bbase, fill, rowptr, nbuck, N, E);
    k_bscatter<<<(E + TILE - 1) / TILE, B, 0, stream>>>(ei, fill, packed, E, nbuck);
    k_bsort<<<nbuck, B, 0, stream>>>(packed, bbase, csr_src, rowptr, dinv, N);

    // --- layer 1 ---
    k_lin1<<<(N + 15) / 16, B, 0, stream>>>(x, W1, dinv, y1, N);
    k_gather<4><<<(N * C1 + B - 1) / B, B, 0, stream>>>(rowptr, csr_src, dinv, y1, agg1, N);

    // --- layer 2 ---
    k_lin2<<<(N + 7) / 8, B, 0, stream>>>(agg1, b1, W2, dinv, y2, N);
    k_gather<5><<<(N * C2 + B - 1) / B, B, 0, stream>>>(rowptr, csr_src, dinv, y2, agg2, N);

    // --- pool + fc ---
    k_pool_fc<<<G, B, 0, stream>>>(agg2, b2, batch, Wfc, bfc, out, N, G);
}

// Round 5
// 202.862 us; speedup vs baseline: 6.4156x; 1.5973x over previous
//
#include <hip/hip_runtime.h>
#include <hip/hip_fp16.h>

#define NF   128
#define C1   16
#define C2   32
#define NCLS 10
#define MAXBUCK 512     // buckets of 256 nodes; N=100000 -> 391
#define TILE 4096       // edges per k_bscatter block
#define HTILE 8192      // edges per k_bhist block
#define CAP 12288       // LDS stage capacity in k_bsort (mean bucket ~8200)

// ============ bucket histogram (LDS-staged) ============

__global__ __launch_bounds__(256) void k_bhist(const int* __restrict__ ei,
                                               int* __restrict__ bcount, int E, int nbuck) {
    __shared__ int h[MAXBUCK];
    int tid = threadIdx.x;
    for (int i = tid; i < MAXBUCK; i += 256) h[i] = 0;
    __syncthreads();
    long long t0 = (long long)blockIdx.x * HTILE;
    for (int i = tid; i < HTILE; i += 256) {
        long long e = t0 + i;
        if (e < E) atomicAdd(&h[ei[E + e] >> 8], 1);
    }
    __syncthreads();
    for (int i = tid; i < nbuck; i += 256)
        if (h[i]) atomicAdd(&bcount[i], h[i]);
}

// exclusive scan of bucket counts -> bbase[0..nbuck]; init fill = bbase; rowptr[N]=E
__global__ __launch_bounds__(512) void k_bucket_scan(const int* __restrict__ bcount,
                                                     int* __restrict__ bbase,
                                                     int* __restrict__ fill,
                                                     int* __restrict__ rowptr,
                                                     int nbuck, int N, int E) {
    __shared__ int sh[512];
    int tid = threadIdx.x;
    int v = (tid < nbuck) ? bcount[tid] : 0;
    sh[tid] = v;
    __syncthreads();
    for (int off = 1; off < 512; off <<= 1) {
        int t = (tid >= off) ? sh[tid - off] : 0;
        __syncthreads();
        sh[tid] += t;
        __syncthreads();
    }
    if (tid < nbuck) {
        int ex = sh[tid] - v;
        bbase[tid] = ex;
        fill[tid] = ex;
    }
    if (tid == 0) { bbase[nbuck] = E; rowptr[N] = E; }
}

// ============ bucketed edge binning: packed = src | (dst&255)<<17, bucket-contiguous ============

__global__ __launch_bounds__(256) void k_bscatter(const int* __restrict__ ei,
                                                  int* __restrict__ fill,
                                                  int* __restrict__ packed_out,
                                                  int E, int nbuck) {
    __shared__ int hist[MAXBUCK];
    __shared__ int off0[MAXBUCK];
    __shared__ int cur[MAXBUCK];
    __shared__ int basev[MAXBUCK];
    __shared__ int stage[TILE];            // 16 KB
    __shared__ unsigned short bkt[TILE];   // 8 KB
    int tid = threadIdx.x;
    long long t0 = (long long)blockIdx.x * TILE;

    for (int i = tid; i < MAXBUCK; i += 256) hist[i] = 0;
    __syncthreads();
    for (int i = tid; i < TILE; i += 256) {
        long long e = t0 + i;
        if (e < E) atomicAdd(&hist[ei[E + e] >> 8], 1);
    }
    __syncthreads();
    if (tid < 64) {
        int carry = 0;
        for (int c = 0; c < MAXBUCK / 64; ++c) {
            int idx = c * 64 + tid;
            int v = hist[idx];
            int orig = v;
            for (int off = 1; off < 64; off <<= 1) {
                int t = __shfl_up(v, off);
                if (tid >= off) v += t;
            }
            off0[idx] = v - orig + carry;
            carry += __shfl(v, 63);
        }
    }
    __syncthreads();
    for (int i = tid; i < nbuck; i += 256) {
        int h = hist[i];
        basev[i] = h ? atomicAdd(&fill[i], h) : 0;
        cur[i] = off0[i];
    }
    __syncthreads();
    for (int i = tid; i < TILE; i += 256) {
        long long e = t0 + i;
        if (e < E) {
            int d = ei[E + e];
            int s = ei[e];
            int b = d >> 8;
            int slot = atomicAdd(&cur[b], 1);
            stage[slot] = s | ((d & 255) << 17);
            bkt[slot] = (unsigned short)b;
        }
    }
    __syncthreads();
    int m = (int)min((long long)TILE, (long long)E - t0);
    for (int i = tid; i < m; i += 256) {
        int b = bkt[i];
        packed_out[basev[b] + (i - off0[b])] = stage[i];
    }
}

// ============ within-bucket counting sort -> csr_src, rowptr, dinv ============

__global__ __launch_bounds__(256) void k_bsort(const int* __restrict__ packed,
                                               const int* __restrict__ bbase,
                                               int* __restrict__ csr_src,
                                               int* __restrict__ rowptr,
                                               float* __restrict__ dinv, int N) {
    __shared__ int stage[CAP];   // 48 KB
    __shared__ int hcnt[256];
    __shared__ int sh[256];
    __shared__ int cur[256];
    int tid = threadIdx.x, b = blockIdx.x;
    int e0 = bbase[b], e1 = bbase[b + 1], m = e1 - e0;
    int n0 = b << 8;
    hcnt[tid] = 0;
    __syncthreads();
    bool staged = (m <= CAP);
    if (staged) {
        for (int i = tid; i < m; i += 256) {
            int p = packed[e0 + i];
            stage[i] = p;
            atomicAdd(&hcnt[p >> 17], 1);
        }
    } else {
        for (int i = tid; i < m; i += 256)
            atomicAdd(&hcnt[packed[e0 + i] >> 17], 1);
    }
    __syncthreads();
    int v = hcnt[tid];
    sh[tid] = v;
    __syncthreads();
    for (int off = 1; off < 256; off <<= 1) {
        int t = (tid >= off) ? sh[tid - off] : 0;
        __syncthreads();
        sh[tid] += t;
        __syncthreads();
    }
    int ex = sh[tid] - v;
    cur[tid] = ex;
    int n = n0 + tid;
    if (n < N) {
        rowptr[n] = e0 + ex;
        dinv[n] = rsqrtf((float)v + 1.0f);   // +1 self-loop
    }
    __syncthreads();
    if (staged) {
        for (int i = tid; i < m; i += 256) {
            int p = stage[i];
            int slot = atomicAdd(&cur[p >> 17], 1);
            csr_src[e0 + slot] = p & 0x1FFFF;
        }
    } else {
        for (int i = tid; i < m; i += 256) {
            int p = packed[e0 + i];
            int slot = atomicAdd(&cur[p >> 17], 1);
            csr_src[e0 + slot] = p & 0x1FFFF;
        }
    }
}

// ============ linear 1: y1h = half((x @ W1) * dinv)  [N,16] fp16 ============

__global__ __launch_bounds__(256) void k_lin1(const float* __restrict__ x,
                                              const float* __restrict__ W1,
                                              const float* __restrict__ dinv,
                                              __half* __restrict__ y1h, int N) {
    __shared__ float ws[NF * C1];
    __shared__ float xs[16 * 132];
    int tid = threadIdx.x;
    for (int t = tid; t < NF * C1; t += 256) ws[t] = W1[t];
    int n0 = blockIdx.x * 16;
    for (int t = tid; t < 16 * NF; t += 256) {
        int r = t >> 7, c = t & 127;
        int n = n0 + r;
        xs[r * 132 + c] = (n < N) ? x[(size_t)n * NF + c] : 0.0f;
    }
    __syncthreads();
    int r = tid >> 4, j = tid & 15;
    float acc = 0.0f;
#pragma unroll 4
    for (int k = 0; k < NF; ++k) acc += xs[r * 132 + k] * ws[k * C1 + j];
    int n = n0 + r;
    if (n < N) y1h[(size_t)n * C1 + j] = __float2half_rn(acc * dinv[n]);
}

// ============ fp16 gather in 16-dim: agg[n] = dinv[n]*(y[n] + sum y[src])  (f32 accum) ============

__global__ __launch_bounds__(256) void k_gather_h(const int* __restrict__ rowptr,
                                                  const int* __restrict__ csr_src,
                                                  const float* __restrict__ dinv,
                                                  const __half2* __restrict__ yh,
                                                  float2* __restrict__ agg, int N) {
    int tid = threadIdx.x;
    int j = tid & 7;                       // half2 lane within row (16 halfs = 8 half2)
    int n = blockIdx.x * 32 + (tid >> 3);
    if (n >= N) return;
    int k0 = rowptr[n], k1 = rowptr[n + 1];
    float2 self = __half22float2(yh[(size_t)n * 8 + j]);
    float a0 = self.x, a1 = self.y;
    float b0 = 0.f, b1 = 0.f, c0 = 0.f, c1 = 0.f, d0 = 0.f, d1 = 0.f;
    int k = k0;
    for (; k + 3 < k1; k += 4) {
        int s0 = csr_src[k], s1 = csr_src[k + 1], s2 = csr_src[k + 2], s3 = csr_src[k + 3];
        float2 v0 = __half22float2(yh[(size_t)s0 * 8 + j]);
        float2 v1 = __half22float2(yh[(size_t)s1 * 8 + j]);
        float2 v2 = __half22float2(yh[(size_t)s2 * 8 + j]);
        float2 v3 = __half22float2(yh[(size_t)s3 * 8 + j]);
        a0 += v0.x; a1 += v0.y; b0 += v1.x; b1 += v1.y;
        c0 += v2.x; c1 += v2.y; d0 += v3.x; d1 += v3.y;
    }
    for (; k < k1; ++k) {
        float2 v = __half22float2(yh[(size_t)csr_src[k] * 8 + j]);
        a0 += v.x; a1 += v.y;
    }
    float dn = dinv[n];
    float2 r;
    r.x = dn * ((a0 + b0) + (c0 + d0));
    r.y = dn * ((a1 + b1) + (c1 + d1));
    agg[(size_t)n * 8 + j] = r;
}

// ============ u = half(relu(agg1 + b1) * dinv)  [N,16] fp16 ============

__global__ __launch_bounds__(256) void k_uprep(const float2* __restrict__ agg1,
                                               const float* __restrict__ b1,
                                               const float* __restrict__ dinv,
                                               __half2* __restrict__ uh, int N) {
    int i = blockIdx.x * blockDim.x + threadIdx.x;   // over N*8 half2s
    if (i >= N * 8) return;
    int n = i >> 3, j = i & 7;
    float2 a = agg1[i];
    float dn = dinv[n];
    float u0 = fmaxf(a.x + b1[2 * j], 0.0f) * dn;
    float u1 = fmaxf(a.y + b1[2 * j + 1], 0.0f) * dn;
    uh[i] = __floats2half2_rn(u0, u1);
}

// ============ pool + W2 + relu + FC fused (per graph; sorted batch) ============
// h2[n] = relu(z[n] @ W2 + b2); pooled = mean h2; out = pooled @ Wfc + bfc

__global__ __launch_bounds__(256) void k_pool_fc(const float* __restrict__ z,
                                                 const float* __restrict__ W2,
                                                 const float* __restrict__ b2,
                                                 const int* __restrict__ batch,
                                                 const float* __restrict__ Wfc,
                                                 const float* __restrict__ bfc,
                                                 float* __restrict__ out, int N, int G) {
    __shared__ float W2s[C1 * C2];
    int tid = threadIdx.x;
    for (int t = tid; t < C1 * C2; t += 256) W2s[t] = W2[t];

    int g = blockIdx.x;
    int lo = 0, hi = N;
    while (lo < hi) { int m = (lo + hi) >> 1; if (batch[m] < g) lo = m + 1; else hi = m; }
    int start = lo;
    lo = start; hi = N;
    while (lo < hi) { int m = (lo + hi) >> 1; if (batch[m] < g + 1) lo = m + 1; else hi = m; }
    int end = lo;
    __syncthreads();

    int i = tid & 31, r = tid >> 5;       // 8 node-groups x 32 output channels
    float bi = b2[i];
    float acc = 0.0f;
    for (int n = start + r; n < end; n += 8) {
        const float* zr = &z[(size_t)n * C1];
        float h = bi;
#pragma unroll
        for (int j = 0; j < C1; ++j) h += zr[j] * W2s[j * C2 + i];
        acc += fmaxf(h, 0.0f);
    }

    __shared__ float red[256];
    red[tid] = acc;
    __syncthreads();
    for (int s = 4; s >= 1; s >>= 1) {
        if (r < s) red[tid] += red[tid + s * 32];
        __syncthreads();
    }
    __shared__ float pooled[C2];
    if (tid < C2) {
        float cnt = (float)(end - start);
        pooled[tid] = red[tid] / fmaxf(cnt, 1.0f);
    }
    __syncthreads();
    if (tid < NCLS) {
        float a = bfc[tid];
#pragma unroll
        for (int j = 0; j < C2; ++j) a += pooled[j] * Wfc[j * NCLS + tid];
        out[g * NCLS + tid] = a;
    }
}

extern "C" void kernel_launch(void* const* d_in, const int* in_sizes, int n_in,
                              void* d_out, int out_size, void* d_ws, size_t ws_size,
                              hipStream_t stream) {
    const float* x    = (const float*)d_in[0];
    const int*   ei   = (const int*)d_in[1];
    const int*   batch= (const int*)d_in[2];
    const float* W1   = (const float*)d_in[3];
    const float* b1   = (const float*)d_in[4];
    const float* W2   = (const float*)d_in[5];
    const float* b2   = (const float*)d_in[6];
    const float* Wfc  = (const float*)d_in[7];
    const float* bfc  = (const float*)d_in[8];
    float* out = (float*)d_out;

    const int N = in_sizes[0] / NF;        // 100000
    const int E = in_sizes[1] / 2;         // 3200000
    const int G = out_size / NCLS;         // 256
    const int nbuck = (N + 255) >> 8;      // 391

    char* p = (char*)d_ws;
    auto alloc = [&](size_t bytes) { char* q = p; p += (bytes + 63) & ~(size_t)63; return q; };
    int*     bcount  = (int*)    alloc(MAXBUCK * 4);
    int*     bbase   = (int*)    alloc((MAXBUCK + 1) * 4);
    int*     fill    = (int*)    alloc(MAXBUCK * 4);
    int*     rowptr  = (int*)    alloc((size_t)(N + 1) * 4);
    float*   dinv    = (float*)  alloc((size_t)N * 4);
    int*     packed  = (int*)    alloc((size_t)E * 4);
    int*     csr_src = (int*)    alloc((size_t)E * 4);
    __half*  y1h     = (__half*) alloc((size_t)N * C1 * 2);
    float*   agg1    = (float*)  alloc((size_t)N * C1 * 4);
    __half*  uh      = (__half*) alloc((size_t)N * C1 * 2);
    float*   z       = (float*)  alloc((size_t)N * C1 * 4);

    const int B = 256;

    // --- CSR build ---
    hipMemsetAsync(bcount, 0, MAXBUCK * 4, stream);
    k_bhist<<<(E + HTILE - 1) / HTILE, B, 0, stream>>>(ei, bcount, E, nbuck);
    k_bucket_scan<<<1, 512, 0, stream>>>(bcount, bbase, fill, rowptr, nbuck, N, E);
    k_bscatter<<<(E + TILE - 1) / TILE, B, 0, stream>>>(ei, fill, packed, E, nbuck);
    k_bsort<<<nbuck, B, 0, stream>>>(packed, bbase, csr_src, rowptr, dinv, N);

    // --- layer 1 (16-dim fp16 gather) ---
    k_lin1<<<(N + 15) / 16, B, 0, stream>>>(x, W1, dinv, y1h, N);
    k_gather_h<<<(N + 31) / 32, B, 0, stream>>>(rowptr, csr_src, dinv,
                                                (const __half2*)y1h, (float2*)agg1, N);

    // --- layer 2 (aggregate in 16-dim; W2 commuted into pool) ---
    k_uprep<<<(N * 8 + B - 1) / B, B, 0, stream>>>((const float2*)agg1, b1, dinv,
                                                   (__half2*)uh, N);
    k_gather_h<<<(N + 31) / 32, B, 0, stream>>>(rowptr, csr_src, dinv,
                                                (const __half2*)uh, (float2*)z, N);

    // --- pool + W2 + relu + FC ---
    k_pool_fc<<<G, B, 0, stream>>>(z, W2, b2, batch, Wfc, bfc, out, N, G);
}

// Round 6
// 200.308 us; speedup vs baseline: 6.4974x; 1.0128x over previous
//
#include <hip/hip_runtime.h>
#include <hip/hip_fp16.h>

#define NF   128
#define C1   16
#define C2   32
#define NCLS 10
#define BSH  7          // bucket = 128 nodes
#define BN   128
#define MAXB 1024       // >= nbuck = 782
#define S    5120       // packed/csr stride per bucket (mean 4096 edges, +16 sigma)
#define TILE 4096       // edges per k_bscatter block
#define CAP  6144       // LDS stage capacity in k_bsort

// ============ bucketed edge binning: packed[b*S + rank] = src | (dst&127)<<17 ============

__global__ __launch_bounds__(256) void k_bscatter(const int* __restrict__ ei,
                                                  int* __restrict__ fill,
                                                  int* __restrict__ packed,
                                                  int E, int nbuck) {
    __shared__ int hist[MAXB];
    __shared__ int basev[MAXB];
    __shared__ int cur[MAXB];
    int tid = threadIdx.x;
    long long t0 = (long long)blockIdx.x * TILE;

    for (int i = tid; i < MAXB; i += 256) { hist[i] = 0; cur[i] = 0; }
    __syncthreads();

    int dstv[TILE / 256];
#pragma unroll
    for (int u = 0; u < TILE / 256; ++u) {
        long long e = t0 + tid + u * 256;
        int d = (e < E) ? ei[E + e] : -1;
        dstv[u] = d;
        if (d >= 0) atomicAdd(&hist[d >> BSH], 1);
    }
    __syncthreads();
    for (int i = tid; i < nbuck; i += 256) {
        int h = hist[i];
        basev[i] = h ? atomicAdd(&fill[i], h) : 0;
    }
    __syncthreads();
#pragma unroll
    for (int u = 0; u < TILE / 256; ++u) {
        long long e = t0 + tid + u * 256;
        if (e < E) {
            int d = dstv[u];
            int s = ei[e];
            int b = d >> BSH;
            int rank = basev[b] + atomicAdd(&cur[b], 1);
            packed[(size_t)b * S + rank] = s | ((d & (BN - 1)) << 17);
        }
    }
}

// ============ within-bucket counting sort -> csr, rowptr, deg, dinv ============

__global__ __launch_bounds__(256) void k_bsort(const int* __restrict__ packed,
                                               const int* __restrict__ fill,
                                               int* __restrict__ csr,
                                               int* __restrict__ rowptr,
                                               int* __restrict__ deg,
                                               float* __restrict__ dinv, int N) {
    __shared__ int stage[CAP];     // 24 KB
    __shared__ int hcnt[BN];
    __shared__ int sh[BN];
    __shared__ int cur[BN];
    int tid = threadIdx.x, b = blockIdx.x;
    int m = fill[b];
    size_t base = (size_t)b * S;
    int n0 = b << BSH;
    if (tid < BN) hcnt[tid] = 0;
    __syncthreads();
    bool staged = (m <= CAP);
    if (staged) {
        for (int i = tid; i < m; i += 256) {
            int p = packed[base + i];
            stage[i] = p;
            atomicAdd(&hcnt[p >> 17], 1);
        }
    } else {
        for (int i = tid; i < m; i += 256)
            atomicAdd(&hcnt[packed[base + i] >> 17], 1);
    }
    __syncthreads();
    if (tid < BN) sh[tid] = hcnt[tid];
    __syncthreads();
    for (int off = 1; off < BN; off <<= 1) {
        int t = (tid < BN && tid >= off) ? sh[tid - off] : 0;
        __syncthreads();
        if (tid < BN) sh[tid] += t;
        __syncthreads();
    }
    if (tid < BN) {
        int v = hcnt[tid];
        int ex = sh[tid] - v;
        cur[tid] = ex;
        int n = n0 + tid;
        if (n < N) {
            rowptr[n] = (int)base + ex;
            deg[n] = v;
            dinv[n] = rsqrtf((float)v + 1.0f);   // +1 self-loop
        }
    }
    __syncthreads();
    if (staged) {
        for (int i = tid; i < m; i += 256) {
            int p = stage[i];
            int slot = atomicAdd(&cur[p >> 17], 1);
            csr[base + slot] = p & 0x1FFFF;
        }
    } else {
        for (int i = tid; i < m; i += 256) {
            int p = packed[base + i];
            int slot = atomicAdd(&cur[p >> 17], 1);
            csr[base + slot] = p & 0x1FFFF;
        }
    }
}

// ============ linear 1: y1h = half((x @ W1) * dinv)  [N,16] fp16 ============

__global__ __launch_bounds__(256) void k_lin1(const float* __restrict__ x,
                                              const float* __restrict__ W1,
                                              const float* __restrict__ dinv,
                                              __half* __restrict__ y1h, int N) {
    __shared__ float ws[NF * C1];
    __shared__ float xs[16 * 132];
    int tid = threadIdx.x;
    for (int t = tid; t < NF * C1; t += 256) ws[t] = W1[t];
    int n0 = blockIdx.x * 16;
    for (int t = tid; t < 16 * NF; t += 256) {
        int r = t >> 7, c = t & 127;
        int n = n0 + r;
        xs[r * 132 + c] = (n < N) ? x[(size_t)n * NF + c] : 0.0f;
    }
    __syncthreads();
    int r = tid >> 4, j = tid & 15;
    float acc = 0.0f;
#pragma unroll 4
    for (int k = 0; k < NF; ++k) acc += xs[r * 132 + k] * ws[k * C1 + j];
    int n = n0 + r;
    if (n < N) y1h[(size_t)n * C1 + j] = __float2half_rn(acc * dinv[n]);
}

// ============ fp16 gather (16-dim, f32 accum) ============
// MODE 0: out = float2 agg = dinv*(self + sum)          (feeds pool_fc)
// MODE 1: out = half2  u  = relu(agg + b1)*dinv         (feeds 2nd gather)

template <int MODE>
__global__ __launch_bounds__(256) void k_gather_h(const int* __restrict__ rowptr,
                                                  const int* __restrict__ deg,
                                                  const int* __restrict__ csr,
                                                  const float* __restrict__ dinv,
                                                  const float* __restrict__ bias,
                                                  const __half2* __restrict__ yh,
                                                  void* __restrict__ outp, int N) {
    int tid = threadIdx.x;
    int j = tid & 7;                       // half2 lane within row
    int n = blockIdx.x * 32 + (tid >> 3);
    if (n >= N) return;
    int k0 = rowptr[n];
    int k1 = k0 + deg[n];
    float2 self = __half22float2(yh[(size_t)n * 8 + j]);
    float a0 = self.x, a1 = self.y;
    float e0 = 0.f, e1 = 0.f, f0 = 0.f, f1 = 0.f, g0 = 0.f, g1 = 0.f;
    int k = k0;
    for (; k + 3 < k1; k += 4) {
        int s0 = csr[k], s1 = csr[k + 1], s2 = csr[k + 2], s3 = csr[k + 3];
        float2 v0 = __half22float2(yh[(size_t)s0 * 8 + j]);
        float2 v1 = __half22float2(yh[(size_t)s1 * 8 + j]);
        float2 v2 = __half22float2(yh[(size_t)s2 * 8 + j]);
        float2 v3 = __half22float2(yh[(size_t)s3 * 8 + j]);
        a0 += v0.x; a1 += v0.y; e0 += v1.x; e1 += v1.y;
        f0 += v2.x; f1 += v2.y; g0 += v3.x; g1 += v3.y;
    }
    for (; k < k1; ++k) {
        float2 v = __half22float2(yh[(size_t)csr[k] * 8 + j]);
        a0 += v.x; a1 += v.y;
    }
    float dn = dinv[n];
    float rx = dn * ((a0 + e0) + (f0 + g0));
    float ry = dn * ((a1 + e1) + (f1 + g1));
    if (MODE == 0) {
        ((float2*)outp)[(size_t)n * 8 + j] = make_float2(rx, ry);
    } else {
        float2 bb = ((const float2*)bias)[j];
        float u0 = fmaxf(rx + bb.x, 0.0f) * dn;
        float u1 = fmaxf(ry + bb.y, 0.0f) * dn;
        ((__half2*)outp)[(size_t)n * 8 + j] = __floats2half2_rn(u0, u1);
    }
}

// ============ pool + W2 + relu + FC fused (per graph; sorted batch) ============

__global__ __launch_bounds__(256) void k_pool_fc(const float* __restrict__ z,
                                                 const float* __restrict__ W2,
                                                 const float* __restrict__ b2,
                                                 const int* __restrict__ batch,
                                                 const float* __restrict__ Wfc,
                                                 const float* __restrict__ bfc,
                                                 float* __restrict__ out, int N, int G) {
    __shared__ float W2s[C1 * C2];
    int tid = threadIdx.x;
    for (int t = tid; t < C1 * C2; t += 256) W2s[t] = W2[t];

    int g = blockIdx.x;
    int lo = 0, hi = N;
    while (lo < hi) { int m = (lo + hi) >> 1; if (batch[m] < g) lo = m + 1; else hi = m; }
    int start = lo;
    lo = start; hi = N;
    while (lo < hi) { int m = (lo + hi) >> 1; if (batch[m] < g + 1) lo = m + 1; else hi = m; }
    int end = lo;
    __syncthreads();

    int i = tid & 31, r = tid >> 5;       // 8 node-groups x 32 output channels
    float bi = b2[i];
    float acc = 0.0f;
    for (int n = start + r; n < end; n += 8) {
        const float* zr = &z[(size_t)n * C1];
        float h = bi;
#pragma unroll
        for (int j = 0; j < C1; ++j) h += zr[j] * W2s[j * C2 + i];
        acc += fmaxf(h, 0.0f);
    }

    __shared__ float red[256];
    red[tid] = acc;
    __syncthreads();
    for (int s = 4; s >= 1; s >>= 1) {
        if (r < s) red[tid] += red[tid + s * 32];
        __syncthreads();
    }
    __shared__ float pooled[C2];
    if (tid < C2) {
        float cnt = (float)(end - start);
        pooled[tid] = red[tid] / fmaxf(cnt, 1.0f);
    }
    __syncthreads();
    if (tid < NCLS) {
        float a = bfc[tid];
#pragma unroll
        for (int j = 0; j < C2; ++j) a += pooled[j] * Wfc[j * NCLS + tid];
        out[g * NCLS + tid] = a;
    }
}

extern "C" void kernel_launch(void* const* d_in, const int* in_sizes, int n_in,
                              void* d_out, int out_size, void* d_ws, size_t ws_size,
                              hipStream_t stream) {
    const float* x    = (const float*)d_in[0];
    const int*   ei   = (const int*)d_in[1];
    const int*   batch= (const int*)d_in[2];
    const float* W1   = (const float*)d_in[3];
    const float* b1   = (const float*)d_in[4];
    const float* W2   = (const float*)d_in[5];
    const float* b2   = (const float*)d_in[6];
    const float* Wfc  = (const float*)d_in[7];
    const float* bfc  = (const float*)d_in[8];
    float* out = (float*)d_out;

    const int N = in_sizes[0] / NF;        // 100000
    const int E = in_sizes[1] / 2;         // 3200000
    const int G = out_size / NCLS;         // 256
    const int nbuck = (N + BN - 1) >> BSH; // 782

    char* p = (char*)d_ws;
    auto alloc = [&](size_t bytes) { char* q = p; p += (bytes + 63) & ~(size_t)63; return q; };
    int*     fill    = (int*)    alloc(MAXB * 4);
    int*     rowptr  = (int*)    alloc((size_t)N * 4);
    int*     deg     = (int*)    alloc((size_t)N * 4);
    float*   dinv    = (float*)  alloc((size_t)N * 4);
    int*     packed  = (int*)    alloc((size_t)nbuck * S * 4);   // 16 MB
    int*     csr     = (int*)    alloc((size_t)nbuck * S * 4);   // 16 MB
    __half*  y1h     = (__half*) alloc((size_t)N * C1 * 2);
    __half*  uh      = (__half*) alloc((size_t)N * C1 * 2);
    float*   z       = (float*)  alloc((size_t)N * C1 * 4);

    const int B = 256;

    // --- CSR build (strided buckets; no pre-histogram pass) ---
    hipMemsetAsync(fill, 0, MAXB * 4, stream);
    k_bscatter<<<(E + TILE - 1) / TILE, B, 0, stream>>>(ei, fill, packed, E, nbuck);
    k_bsort<<<nbuck, B, 0, stream>>>(packed, fill, csr, rowptr, deg, dinv, N);

    // --- layer 1 + fused relu/b1/dinv epilogue ---
    k_lin1<<<(N + 15) / 16, B, 0, stream>>>(x, W1, dinv, y1h, N);
    k_gather_h<1><<<(N + 31) / 32, B, 0, stream>>>(rowptr, deg, csr, dinv, b1,
                                                   (const __half2*)y1h, uh, N);

    // --- layer 2 aggregation (16-dim; W2 commuted into pool) ---
    k_gather_h<0><<<(N + 31) / 32, B, 0, stream>>>(rowptr, deg, csr, dinv, b1,
                                                   (const __half2*)uh, z, N);

    // --- pool + W2 + relu + FC ---
    k_pool_fc<<<G, B, 0, stream>>>(z, W2, b2, batch, Wfc, bfc, out, N, G);
}

// Round 8
// 199.932 us; speedup vs baseline: 6.5096x; 1.0019x over previous
//
#include <hip/hip_runtime.h>
#include <hip/hip_fp16.h>

#define NF   128
#define C1   16
#define C2   32
#define NCLS 10
#define BSH  8          // bucket = 256 nodes
#define BN   256
#define MAXB 512        // >= nbuck = 391
#define S    9216       // packed/csr stride per bucket (mean 8192, +11 sigma)
#define TILE 2048       // edges per k_bscatter block
#define CAPQ 3072       // LDS stage capacity per quarter in k_bsort (mean 2048, +22 sigma)
#define EPT  (TILE/256)

// ============ bucketed edge binning: packed[b*S + rank] = src | (local_dst<<17) ============
// staged in LDS, copied out bucket-ordered (coalesced runs)

__global__ __launch_bounds__(256) void k_bscatter(const int* __restrict__ ei,
                                                  int* __restrict__ fill,
                                                  int* __restrict__ packed,
                                                  int E, int nbuck) {
    __shared__ int hist[MAXB];
    __shared__ int off0[MAXB];
    __shared__ int cur[MAXB];
    __shared__ int basev[MAXB];
    __shared__ int stage[TILE];              // 8 KB
    __shared__ unsigned short bkt[TILE];     // 4 KB
    int tid = threadIdx.x;
    long long t0 = (long long)blockIdx.x * TILE;

    for (int i = tid; i < MAXB; i += 256) hist[i] = 0;
    __syncthreads();

    int dstv[EPT], srcv[EPT];
#pragma unroll
    for (int u = 0; u < EPT; ++u) {
        long long e = t0 + tid + u * 256;
        int d = -1, s = 0;
        if (e < E) { d = ei[E + e]; s = ei[e]; }
        dstv[u] = d; srcv[u] = s;
        if (d >= 0) atomicAdd(&hist[d >> BSH], 1);
    }
    __syncthreads();
    // exclusive scan of hist[0..MAXB) by wave 0; cur = off0 (INCLUDING cross-chunk carry)
    if (tid < 64) {
        int carry = 0;
        for (int c = 0; c < MAXB / 64; ++c) {
            int idx = c * 64 + tid;
            int v = hist[idx];
            int orig = v;
            for (int off = 1; off < 64; off <<= 1) {
                int t = __shfl_up(v, off);
                if (tid >= off) v += t;
            }
            int ex = v - orig + carry;
            off0[idx] = ex;
            cur[idx] = ex;
            carry += __shfl(v, 63);
        }
    }
    __syncthreads();
    for (int i = tid; i < nbuck; i += 256) {
        int h = hist[i];
        basev[i] = h ? atomicAdd(&fill[i], h) : 0;
    }
    __syncthreads();
#pragma unroll
    for (int u = 0; u < EPT; ++u) {
        int d = dstv[u];
        if (d >= 0) {
            int b = d >> BSH;
            int slot = atomicAdd(&cur[b], 1);
            stage[slot] = srcv[u] | ((d & (BN - 1)) << 17);
            bkt[slot] = (unsigned short)b;
        }
    }
    __syncthreads();
    int m = (int)min((long long)TILE, (long long)E - t0);
    for (int i = tid; i < m; i += 256) {
        int b = bkt[i];
        packed[(size_t)b * S + basev[b] + (i - off0[b])] = stage[i];
    }
}

// ============ within-bucket counting sort, quarter-split ============
// block = (bucket, quarter of 64 nodes); scans whole bucket region, stages its quarter

__global__ __launch_bounds__(256) void k_bsort(const int* __restrict__ packed,
                                               const int* __restrict__ fill,
                                               int* __restrict__ csr,
                                               int* __restrict__ rowptr,
                                               int* __restrict__ deg,
                                               float* __restrict__ dinv, int N) {
    __shared__ int stage[CAPQ];    // 12 KB
    __shared__ int hcnt[BN];
    __shared__ int sh[BN];
    __shared__ int cur[BN];
    __shared__ int qn;
    int tid = threadIdx.x;
    int B = blockIdx.x >> 2, q = blockIdx.x & 3;
    int m = fill[B];
    size_t base = (size_t)B * S;
    int lo_q = q * 64, hi_q = lo_q + 64;

    hcnt[tid] = 0;
    if (tid == 0) qn = 0;
    __syncthreads();

    for (int i = tid; i < m; i += 256) {
        int p = packed[base + i];
        int l = p >> 17;
        atomicAdd(&hcnt[l], 1);
        if (l >= lo_q && l < hi_q) {
            int sp = atomicAdd(&qn, 1);
            if (sp < CAPQ) stage[sp] = p;
        }
    }
    __syncthreads();
    int v = hcnt[tid];
    sh[tid] = v;
    __syncthreads();
    for (int off = 1; off < BN; off <<= 1) {
        int t = (tid >= off) ? sh[tid - off] : 0;
        __syncthreads();
        sh[tid] += t;
        __syncthreads();
    }
    int ex = sh[tid] - v;
    cur[tid] = ex;
    if (tid >= lo_q && tid < hi_q) {
        int n = (B << BSH) + tid;
        if (n < N) {
            rowptr[n] = (int)base + ex;
            deg[n] = v;
            dinv[n] = rsqrtf((float)v + 1.0f);   // +1 self-loop
        }
    }
    __syncthreads();
    int qm = qn;
    if (qm <= CAPQ) {
        for (int i = tid; i < qm; i += 256) {
            int p = stage[i];
            int slot = atomicAdd(&cur[p >> 17], 1);
            csr[base + slot] = p & 0x1FFFF;
        }
    } else {  // statistically impossible fallback: re-read region
        for (int i = tid; i < m; i += 256) {
            int p = packed[base + i];
            int l = p >> 17;
            if (l >= lo_q && l < hi_q) {
                int slot = atomicAdd(&cur[l], 1);
                csr[base + slot] = p & 0x1FFFF;
            }
        }
    }
}

// ============ linear 1: y1h = half((x @ W1) * dinv)  [N,16] fp16 ============

__global__ __launch_bounds__(256) void k_lin1(const float* __restrict__ x,
                                              const float* __restrict__ W1,
                                              const float* __restrict__ dinv,
                                              __half* __restrict__ y1h, int N) {
    __shared__ float ws[NF * C1];
    __shared__ float xs[16 * 132];
    int tid = threadIdx.x;
    for (int t = tid; t < NF * C1; t += 256) ws[t] = W1[t];
    int n0 = blockIdx.x * 16;
    const float4* x4 = (const float4*)x;
    for (int t = tid; t < 16 * 32; t += 256) {
        int r = t >> 5, c = t & 31;
        int n = n0 + r;
        float4 v = (n < N) ? x4[(size_t)n * 32 + c] : make_float4(0.f, 0.f, 0.f, 0.f);
        float* d = &xs[r * 132 + c * 4];
        d[0] = v.x; d[1] = v.y; d[2] = v.z; d[3] = v.w;
    }
    __syncthreads();
    int r = tid >> 4, j = tid & 15;
    float acc = 0.0f;
#pragma unroll 4
    for (int k = 0; k < NF; ++k) acc += xs[r * 132 + k] * ws[k * C1 + j];
    int n = n0 + r;
    if (n < N) y1h[(size_t)n * C1 + j] = __float2half_rn(acc * dinv[n]);
}

// ============ fp16 gather (16-dim, f32 accum) ============
// MODE 0: out = float2 agg = dinv*(self + sum)          (feeds pool_fc)
// MODE 1: out = half2  u  = relu(agg + b1)*dinv         (feeds 2nd gather)

template <int MODE>
__global__ __launch_bounds__(256) void k_gather_h(const int* __restrict__ rowptr,
                                                  const int* __restrict__ deg,
                                                  const int* __restrict__ csr,
                                                  const float* __restrict__ dinv,
                                                  const float* __restrict__ bias,
                                                  const __half2* __restrict__ yh,
                                                  void* __restrict__ outp, int N) {
    int tid = threadIdx.x;
    int j = tid & 7;                       // half2 lane within row
    int n = blockIdx.x * 32 + (tid >> 3);
    if (n >= N) return;
    int k0 = rowptr[n];
    int k1 = k0 + deg[n];
    float2 self = __half22float2(yh[(size_t)n * 8 + j]);
    float a0 = self.x, a1 = self.y;
    float e0 = 0.f, e1 = 0.f, f0 = 0.f, f1 = 0.f, g0 = 0.f, g1 = 0.f;
    int k = k0;
    for (; k + 3 < k1; k += 4) {
        int s0 = csr[k], s1 = csr[k + 1], s2 = csr[k + 2], s3 = csr[k + 3];
        float2 v0 = __half22float2(yh[(size_t)s0 * 8 + j]);
        float2 v1 = __half22float2(yh[(size_t)s1 * 8 + j]);
        float2 v2 = __half22float2(yh[(size_t)s2 * 8 + j]);
        float2 v3 = __half22float2(yh[(size_t)s3 * 8 + j]);
        a0 += v0.x; a1 += v0.y; e0 += v1.x; e1 += v1.y;
        f0 += v2.x; f1 += v2.y; g0 += v3.x; g1 += v3.y;
    }
    for (; k < k1; ++k) {
        float2 v = __half22float2(yh[(size_t)csr[k] * 8 + j]);
        a0 += v.x; a1 += v.y;
    }
    float dn = dinv[n];
    float rx = dn * ((a0 + e0) + (f0 + g0));
    float ry = dn * ((a1 + e1) + (f1 + g1));
    if (MODE == 0) {
        ((float2*)outp)[(size_t)n * 8 + j] = make_float2(rx, ry);
    } else {
        float2 bb = ((const float2*)bias)[j];
        float u0 = fmaxf(rx + bb.x, 0.0f) * dn;
        float u1 = fmaxf(ry + bb.y, 0.0f) * dn;
        ((__half2*)outp)[(size_t)n * 8 + j] = __floats2half2_rn(u0, u1);
    }
}

// ============ pool + W2 + relu + FC fused (per graph; sorted batch) ============

__global__ __launch_bounds__(256) void k_pool_fc(const float* __restrict__ z,
                                                 const float* __restrict__ W2,
                                                 const float* __restrict__ b2,
                                                 const int* __restrict__ batch,
                                                 const float* __restrict__ Wfc,
                                                 const float* __restrict__ bfc,
                                                 float* __restrict__ out, int N, int G) {
    __shared__ float W2s[C1 * C2];
    int tid = threadIdx.x;
    for (int t = tid; t < C1 * C2; t += 256) W2s[t] = W2[t];

    int g = blockIdx.x;
    int lo = 0, hi = N;
    while (lo < hi) { int m = (lo + hi) >> 1; if (batch[m] < g) lo = m + 1; else hi = m; }
    int start = lo;
    lo = start; hi = N;
    while (lo < hi) { int m = (lo + hi) >> 1; if (batch[m] < g + 1) lo = m + 1; else hi = m; }
    int end = lo;
    __syncthreads();

    int i = tid & 31, r = tid >> 5;       // 8 node-groups x 32 output channels
    float bi = b2[i];
    float acc = 0.0f;
    for (int n = start + r; n < end; n += 8) {
        const float* zr = &z[(size_t)n * C1];
        float h = bi;
#pragma unroll
        for (int j = 0; j < C1; ++j) h += zr[j] * W2s[j * C2 + i];
        acc += fmaxf(h, 0.0f);
    }

    __shared__ float red[256];
    red[tid] = acc;
    __syncthreads();
    for (int s = 4; s >= 1; s >>= 1) {
        if (r < s) red[tid] += red[tid + s * 32];
        __syncthreads();
    }
    __shared__ float pooled[C2];
    if (tid < C2) {
        float cnt = (float)(end - start);
        pooled[tid] = red[tid] / fmaxf(cnt, 1.0f);
    }
    __syncthreads();
    if (tid < NCLS) {
        float a = bfc[tid];
#pragma unroll
        for (int j = 0; j < C2; ++j) a += pooled[j] * Wfc[j * NCLS + tid];
        out[g * NCLS + tid] = a;
    }
}

extern "C" void kernel_launch(void* const* d_in, const int* in_sizes, int n_in,
                              void* d_out, int out_size, void* d_ws, size_t ws_size,
                              hipStream_t stream) {
    const float* x    = (const float*)d_in[0];
    const int*   ei   = (const int*)d_in[1];
    const int*   batch= (const int*)d_in[2];
    const float* W1   = (const float*)d_in[3];
    const float* b1   = (const float*)d_in[4];
    const float* W2   = (const float*)d_in[5];
    const float* b2   = (const float*)d_in[6];
    const float* Wfc  = (const float*)d_in[7];
    const float* bfc  = (const float*)d_in[8];
    float* out = (float*)d_out;

    const int N = in_sizes[0] / NF;        // 100000
    const int E = in_sizes[1] / 2;         // 3200000
    const int G = out_size / NCLS;         // 256
    const int nbuck = (N + BN - 1) >> BSH; // 391

    char* p = (char*)d_ws;
    auto alloc = [&](size_t bytes) { char* q = p; p += (bytes + 63) & ~(size_t)63; return q; };
    int*     fill    = (int*)    alloc(MAXB * 4);
    int*     rowptr  = (int*)    alloc((size_t)N * 4);
    int*     deg     = (int*)    alloc((size_t)N * 4);
    float*   dinv    = (float*)  alloc((size_t)N * 4);
    int*     packed  = (int*)    alloc((size_t)nbuck * S * 4);   // 14.4 MB
    int*     csr     = (int*)    alloc((size_t)nbuck * S * 4);   // 14.4 MB
    __half*  y1h     = (__half*) alloc((size_t)N * C1 * 2);
    __half*  uh      = (__half*) alloc((size_t)N * C1 * 2);
    float*   z       = (float*)  alloc((size_t)N * C1 * 4);

    const int B = 256;

    // --- CSR build (strided buckets; staged copy-out; quarter-split sort) ---
    hipMemsetAsync(fill, 0, MAXB * 4, stream);
    k_bscatter<<<(E + TILE - 1) / TILE, B, 0, stream>>>(ei, fill, packed, E, nbuck);
    k_bsort<<<nbuck * 4, B, 0, stream>>>(packed, fill, csr, rowptr, deg, dinv, N);

    // --- layer 1 + fused relu/b1/dinv epilogue ---
    k_lin1<<<(N + 15) / 16, B, 0, stream>>>(x, W1, dinv, y1h, N);
    k_gather_h<1><<<(N + 31) / 32, B, 0, stream>>>(rowptr, deg, csr, dinv, b1,
                                                   (const __half2*)y1h, uh, N);

    // --- layer 2 aggregation (16-dim; W2 commuted into pool) ---
    k_gather_h<0><<<(N + 31) / 32, B, 0, stream>>>(rowptr, deg, csr, dinv, b1,
                                                   (const __half2*)uh, z, N);

    // --- pool + W2 + relu + FC ---
    k_pool_fc<<<G, B, 0, stream>>>(z, W2, b2, batch, Wfc, bfc, out, N, G);
}